// Round 16
// baseline (885.312 us; speedup 1.0000x reference)
//
#include <hip/hip_runtime.h>

typedef unsigned int u32;
typedef unsigned short u16;
typedef __attribute__((ext_vector_type(4))) float f32x4;
typedef __attribute__((ext_vector_type(8))) short bf16x8;
typedef __attribute__((ext_vector_type(4))) u32 u32x4;

__device__ __forceinline__ u16 f2bf(float f) {
  u32 u = __builtin_bit_cast(u32, f);
  u = u + 0x7FFFu + ((u >> 16) & 1u);
  return (u16)(u >> 16);
}
__device__ __forceinline__ u32 pack2(float a, float b) {
  return (u32)f2bf(a) | ((u32)f2bf(b) << 16);
}
// Pack two C-frags into one A/B-frag under the consistent k-permutation
// sigma (both operands of the attention-middle MFMAs share it).
__device__ __forceinline__ bf16x8 pack8(f32x4 a, f32x4 b) {
  union { u32 w[4]; bf16x8 v; } u;
  u.w[0] = pack2(a[0], a[1]); u.w[1] = pack2(a[2], a[3]);
  u.w[2] = pack2(b[0], b[1]); u.w[3] = pack2(b[2], b[3]);
  return u.v;
}

#define MFMA(a, b, c) __builtin_amdgcn_mfma_f32_16x16x32_bf16((a), (b), (c), 0, 0, 0)

// LDS fragment read: row-major buffer, XOR-swizzled within 128B window.
__device__ __forceinline__ bf16x8 lds_frag(const char* buf, int rowBytes, int row, int kByte) {
  return *(const bf16x8*)(buf + row * rowBytes + (kByte ^ ((row & 7) << 4)));
}

// window/token -> flat token index in [B,32,32,32] (C-contiguous per token)
__device__ __forceinline__ int tok_global(int blk, int t) {
  int b = blk >> 9, r = blk & 511;
  int wd = r >> 6, wh = (r >> 3) & 7, ww = r & 7;
  int d = wd * 4 + (t >> 4);
  int h = wh * 4 + ((t >> 2) & 3);
  int w = ww * 4 + (t & 3);
  return ((b * 32 + d) * 32 + h) * 32 + w;
}

// Weights -> FRAG-MAJOR blob, NATURAL k order (verified R10):
// w[(o_blk*16 + ks)*512 + lane*8 + p] = bf16 of W[ks*32 + g*8 + p][o_blk*16 + lr]
__global__ void prep_weights(const float* __restrict__ wq, const float* __restrict__ wp,
                             u16* __restrict__ wtq, u16* __restrict__ wtp) {
  int idx = blockIdx.x * 512 + threadIdx.x;
  if (idx < 512 * 1536) {
    int i = idx / 1536, o = idx % 1536;
    int c = i & 31;
    int lane = (c >> 3) * 16 + (o & 15);
    wtq[((size_t)(o >> 4) * 16 + (i >> 5)) * 512 + lane * 8 + (c & 7)] = f2bf(wq[idx]);
  } else {
    int j = idx - 512 * 1536;
    int i = j >> 9, o = j & 511;
    int c = i & 31;
    int lane = (c >> 3) * 16 + (o & 15);
    wtp[((size_t)(o >> 4) * 16 + (i >> 5)) * 512 + lane * 8 + (c & 7)] = f2bf(wp[j]);
  }
}

// Half-tile GEMM pass over 16 K-steps: NI weight frags (full-och rows) x
// 2 own-t-half x-frags per step. Weight frags depth-1 prefetched.
#define GEMM_HALF_AB(WLANE, NI)                                               \
  {                                                                           \
    bf16x8 wfs[2][NI];                                                        \
    _Pragma("unroll") for (int i = 0; i < NI; ++i)                            \
        wfs[0][i] = *(const bf16x8*)((WLANE) + (i * 16 + 0) * 512);           \
    _Pragma("unroll") for (int ks = 0; ks < 16; ++ks) {                       \
      if (ks < 15) {                                                          \
        _Pragma("unroll") for (int i = 0; i < NI; ++i)                        \
            wfs[(ks + 1) & 1][i] =                                            \
                *(const bf16x8*)((WLANE) + (i * 16 + ks + 1) * 512);          \
      }                                                                       \
      bf16x8 bx[2];                                                           \
      const int kByte = ks * 64 + g * 16;                                     \
      _Pragma("unroll") for (int jj = 0; jj < 2; ++jj)                        \
          bx[jj] = lds_frag(smem, 1024, (th * 2 + jj) * 16 + lr, kByte);      \
      __builtin_amdgcn_s_setprio(1);                                          \
      _Pragma("unroll") for (int i = 0; i < NI; ++i)                          \
        _Pragma("unroll") for (int jj = 0; jj < 2; ++jj)                      \
            acc[i][jj] = MFMA(wfs[ks & 1][i], bx[jj], acc[i][jj]);            \
      __builtin_amdgcn_s_setprio(0);                                          \
    }                                                                         \
  }

__global__ __launch_bounds__(1024, 4) void fused_win_attn(
    const float* __restrict__ x, const float* __restrict__ bq, const float* __restrict__ bp,
    const u16* __restrict__ wtq, const u16* __restrict__ wtp, float* __restrict__ out) {
  // 1024 threads = 16 waves = one window; wave = (head = wv>>1, t-half = wv&1).
  // LDS: [0,64K) x [64 tok][512 ch] bf16 swz (-> O -> Y-staging);
  //      [64K,128K) exchange region E (16 waves x 4KB).
  __shared__ char smem[131072];
  char* E = smem + 65536;
  const int tid = threadIdx.x;
  const int wv = tid >> 6;
  const int head = wv >> 1;
  const int th = wv & 1;        // own t-half (tokens th*32 .. th*32+31)
  const int l  = tid & 63;
  const int lr = l & 15;
  const int g  = l >> 4;
  const int blk = blockIdx.x;
  char* Eown = E + wv * 4096 + l * 64;
  char* Epar = E + (wv ^ 1) * 4096 + l * 64;

  // ---- stage x -> LDS bf16 (1024 threads: token = tid>>4, 32-ch seg = tid&15) ----
  {
    const int st = tid >> 4, seg = tid & 15;
    const float* xs = x + (size_t)tok_global(blk, st) * 512 + seg * 32;
    char* dst = smem + st * 1024;
    const int swz = (st & 7) << 4;
    float4 f[8];
#pragma unroll
    for (int i = 0; i < 8; ++i) f[i] = ((const float4*)xs)[i];
#pragma unroll
    for (int i = 0; i < 2; ++i) {
      const int ic = (i + seg) & 1;   // rotate pair to spread banks
      u32x4 w = {pack2(f[4 * ic].x, f[4 * ic].y),         pack2(f[4 * ic].z, f[4 * ic].w),
                 pack2(f[4 * ic + 1].x, f[4 * ic + 1].y), pack2(f[4 * ic + 1].z, f[4 * ic + 1].w)};
      u32x4 w2 = {pack2(f[4 * ic + 2].x, f[4 * ic + 2].y), pack2(f[4 * ic + 2].z, f[4 * ic + 2].w),
                  pack2(f[4 * ic + 3].x, f[4 * ic + 3].y), pack2(f[4 * ic + 3].z, f[4 * ic + 3].w)};
      *(u32x4*)(dst + ((seg * 64 + ic * 32) ^ swz)) = w;
      *(u32x4*)(dst + ((seg * 64 + ic * 32 + 16) ^ swz)) = w2;
    }
  }
  __syncthreads();

  // weight base pointers (frag-major blobs; o_blk strides of 16*512 u16)
  const u16* wqL = wtq + ((size_t)head * 4 * 16) * 512 + l * 8;
  const u16* wkL = wqL + (size_t)512 * 512;
  const u16* wvL = wqL + (size_t)1024 * 512;
  const u16* wpL = wtp + ((size_t)wv * 2 * 16) * 512 + l * 8;

  bf16x8 qp[2][2], ka[4][2], pb[2][2], va[4][2];

  // ======== Q pass: full och 64 x own t-half 32 ========
  {
    f32x4 acc[4][2];
#pragma unroll
    for (int i = 0; i < 4; ++i)
#pragma unroll
      for (int jj = 0; jj < 2; ++jj) acc[i][jj] = (f32x4)0.f;
    GEMM_HALF_AB(wqL, 4);
#pragma unroll
    for (int i = 0; i < 4; ++i) {
      const int och = head * 64 + i * 16 + g * 4;
      f32x4 qb = {bq[och], bq[och + 1], bq[och + 2], bq[och + 3]};
#pragma unroll
      for (int jj = 0; jj < 2; ++jj) acc[i][jj] += qb;
    }
#pragma unroll
    for (int jj = 0; jj < 2; ++jj)
#pragma unroll
      for (int kb = 0; kb < 2; ++kb)
        qp[jj][kb] = pack8(acc[2 * kb][jj], acc[2 * kb + 1][jj]);  // B-frag col t(own), k=d
  }

  // ======== K pass: full och 64 x own s-half 32 ========
  {
    f32x4 acc[4][2];
#pragma unroll
    for (int i = 0; i < 4; ++i)
#pragma unroll
      for (int jj = 0; jj < 2; ++jj) acc[i][jj] = (f32x4)0.f;
    GEMM_HALF_AB(wkL, 4);
#pragma unroll
    for (int i = 0; i < 4; ++i) {
      const int och = 512 + head * 64 + i * 16 + g * 4;
      f32x4 kb = {bq[och], bq[och + 1], bq[och + 2], bq[och + 3]};
#pragma unroll
      for (int jj = 0; jj < 2; ++jj) acc[i][jj] += kb;
    }
    // own ka rows: s-blocks m = th*2 + jj
#pragma unroll
    for (int jj = 0; jj < 2; ++jj)
#pragma unroll
      for (int kb = 0; kb < 2; ++kb)
        ka[th * 2 + jj][kb] = pack8(acc[2 * kb][jj], acc[2 * kb + 1][jj]);  // A-frag row s, k=d
  }

  // ---- X1: exchange ka halves with partner wave (same head, other t-half) ----
#pragma unroll
  for (int jj = 0; jj < 2; ++jj)
#pragma unroll
    for (int kb = 0; kb < 2; ++kb)
      *(bf16x8*)(Eown + (jj * 2 + kb) * 16) = ka[th * 2 + jj][kb];
  __syncthreads();
#pragma unroll
  for (int jj = 0; jj < 2; ++jj)
#pragma unroll
    for (int kb = 0; kb < 2; ++kb)
      ka[(th ^ 1) * 2 + jj][kb] = *(const bf16x8*)(Epar + (jj * 2 + kb) * 16);

  // ======== S^T: full s x own t-half; softmax over s (within wave) ========
  {
    f32x4 sacc[4][2];
#pragma unroll
    for (int m = 0; m < 4; ++m)
#pragma unroll
      for (int jj = 0; jj < 2; ++jj) {
        f32x4 a = (f32x4)0.f;
        a = MFMA(ka[m][0], qp[jj][0], a);
        sacc[m][jj] = MFMA(ka[m][1], qp[jj][1], a);
      }
#pragma unroll
    for (int m = 0; m < 4; ++m)
#pragma unroll
      for (int jj = 0; jj < 2; ++jj)
#pragma unroll
        for (int r = 0; r < 4; ++r) {
          float v = sacc[m][jj][r] * 0.125f;
          sacc[m][jj][r] = fminf(fmaxf(v, -10000.f), 10000.f);
        }
    float mx[2], sm[2];
#pragma unroll
    for (int jj = 0; jj < 2; ++jj) {
      float a0 = fmaxf(fmaxf(sacc[0][jj][0], sacc[0][jj][1]), fmaxf(sacc[0][jj][2], sacc[0][jj][3]));
      float a1 = fmaxf(fmaxf(sacc[1][jj][0], sacc[1][jj][1]), fmaxf(sacc[1][jj][2], sacc[1][jj][3]));
      float a2 = fmaxf(fmaxf(sacc[2][jj][0], sacc[2][jj][1]), fmaxf(sacc[2][jj][2], sacc[2][jj][3]));
      float a3 = fmaxf(fmaxf(sacc[3][jj][0], sacc[3][jj][1]), fmaxf(sacc[3][jj][2], sacc[3][jj][3]));
      mx[jj] = fmaxf(fmaxf(a0, a1), fmaxf(a2, a3));
    }
#pragma unroll
    for (int jj = 0; jj < 2; ++jj) mx[jj] = fmaxf(mx[jj], __shfl_xor(mx[jj], 16));
#pragma unroll
    for (int jj = 0; jj < 2; ++jj) mx[jj] = fmaxf(mx[jj], __shfl_xor(mx[jj], 32));
#pragma unroll
    for (int jj = 0; jj < 2; ++jj) {
      float s0 = 0.f;
#pragma unroll
      for (int m = 0; m < 4; ++m)
#pragma unroll
        for (int r = 0; r < 4; ++r) {
          float p = __expf(sacc[m][jj][r] - mx[jj]);
          sacc[m][jj][r] = p;
          s0 += p;
        }
      sm[jj] = s0;
    }
#pragma unroll
    for (int jj = 0; jj < 2; ++jj) sm[jj] += __shfl_xor(sm[jj], 16);
#pragma unroll
    for (int jj = 0; jj < 2; ++jj) sm[jj] += __shfl_xor(sm[jj], 32);
#pragma unroll
    for (int jj = 0; jj < 2; ++jj) {
      float inv = 1.f / sm[jj];
#pragma unroll
      for (int kb = 0; kb < 2; ++kb)
        pb[jj][kb] = pack8(sacc[2 * kb][jj] * inv, sacc[2 * kb + 1][jj] * inv);  // B-frag col t(own), k=s
    }
  }

  // ======== V pass: own s-half tokens x full d 64 ========
  {
    f32x4 acc[2][4];  // [tt own][ni]
#pragma unroll
    for (int tt = 0; tt < 2; ++tt)
#pragma unroll
      for (int ni = 0; ni < 4; ++ni) acc[tt][ni] = (f32x4)0.f;
    {
      bf16x8 wfs[2][4];
#pragma unroll
      for (int i = 0; i < 4; ++i) wfs[0][i] = *(const bf16x8*)(wvL + (i * 16 + 0) * 512);
#pragma unroll
      for (int ks = 0; ks < 16; ++ks) {
        if (ks < 15) {
#pragma unroll
          for (int i = 0; i < 4; ++i)
            wfs[(ks + 1) & 1][i] = *(const bf16x8*)(wvL + (i * 16 + ks + 1) * 512);
        }
        bf16x8 bx[2];
        const int kByte = ks * 64 + g * 16;
#pragma unroll
        for (int tt = 0; tt < 2; ++tt)
          bx[tt] = lds_frag(smem, 1024, (th * 2 + tt) * 16 + lr, kByte);
        __builtin_amdgcn_s_setprio(1);
#pragma unroll
        for (int tt = 0; tt < 2; ++tt)
#pragma unroll
          for (int ni = 0; ni < 4; ++ni) acc[tt][ni] = MFMA(bx[tt], wfs[ks & 1][ni], acc[tt][ni]);
        __builtin_amdgcn_s_setprio(0);
      }
    }
#pragma unroll
    for (int ni = 0; ni < 4; ++ni) {
      float bv = bq[1024 + head * 64 + ni * 16 + lr];
#pragma unroll
      for (int tt = 0; tt < 2; ++tt) acc[tt][ni] += (f32x4)bv;
      va[ni][th] = pack8(acc[0][ni], acc[1][ni]);   // A-frag row d, k = own s-chunk
    }
  }

  // ---- X2: exchange va halves ----
  __syncthreads();   // X1 reads done everywhere; E reusable
#pragma unroll
  for (int ni = 0; ni < 4; ++ni)
    *(bf16x8*)(Eown + ni * 16) = va[ni][th];
  __syncthreads();
#pragma unroll
  for (int ni = 0; ni < 4; ++ni)
    va[ni][th ^ 1] = *(const bf16x8*)(Epar + ni * 16);

  // ======== O^T: full d x own t-half; write O (x is dead: all V passes done) ========
  __syncthreads();
#pragma unroll
  for (int ni = 0; ni < 4; ++ni)
#pragma unroll
    for (int jj = 0; jj < 2; ++jj) {
      f32x4 a = (f32x4)0.f;
      a = MFMA(va[ni][0], pb[jj][0], a);
      a = MFMA(va[ni][1], pb[jj][1], a);
      int t = (th * 2 + jj) * 16 + lr;
      int cb = (head * 64 + ni * 16 + g * 4) * 2;
      int swz = (t & 7) << 4;
      *(u32*)(smem + t * 1024 + (cb ^ swz))       = pack2(a[0], a[1]);
      *(u32*)(smem + t * 1024 + ((cb + 4) ^ swz)) = pack2(a[2], a[3]);
    }
  __syncthreads();

  // ======== Y = O @ Wproj: each wave own 32 och rows x full t 64 ========
  f32x4 acc[2][4];
#pragma unroll
  for (int i = 0; i < 2; ++i)
#pragma unroll
    for (int j = 0; j < 4; ++j) acc[i][j] = (f32x4)0.f;
  {
    bf16x8 wfs[2][2];
#pragma unroll
    for (int i = 0; i < 2; ++i) wfs[0][i] = *(const bf16x8*)(wpL + (i * 16 + 0) * 512);
#pragma unroll
    for (int ks = 0; ks < 16; ++ks) {
      if (ks < 15) {
#pragma unroll
        for (int i = 0; i < 2; ++i)
          wfs[(ks + 1) & 1][i] = *(const bf16x8*)(wpL + (i * 16 + ks + 1) * 512);
      }
      bf16x8 bx[4];
      const int kByte = ks * 64 + g * 16;
#pragma unroll
      for (int j = 0; j < 4; ++j) bx[j] = lds_frag(smem, 1024, j * 16 + lr, kByte);
      __builtin_amdgcn_s_setprio(1);
#pragma unroll
      for (int i = 0; i < 2; ++i)
#pragma unroll
        for (int j = 0; j < 4; ++j) acc[i][j] = MFMA(wfs[ks & 1][i], bx[j], acc[i][j]);
      __builtin_amdgcn_s_setprio(0);
    }
  }
#pragma unroll
  for (int i = 0; i < 2; ++i) {
    const int och = wv * 32 + i * 16 + g * 4;
    f32x4 bb = {bp[och], bp[och + 1], bp[och + 2], bp[och + 3]};
#pragma unroll
    for (int j = 0; j < 4; ++j) acc[i][j] += bb;
  }

  // ======== Epilogue: stage Y via LDS halves, coalesced f32 stores ========
#pragma unroll
  for (int th2 = 0; th2 < 2; ++th2) {
    __syncthreads();
#pragma unroll
    for (int i = 0; i < 2; ++i)
#pragma unroll
      for (int jj = 0; jj < 2; ++jj) {
        const int tj = th2 * 2 + jj;
        const int tl = (tj * 16 + lr) & 31;
        const int ochb = (wv * 32 + i * 16 + g * 4) * 4;
        *(f32x4*)(smem + tl * 2048 + (ochb ^ ((tl & 7) << 4))) = acc[i][tj];
      }
    __syncthreads();
#pragma unroll
    for (int it = 0; it < 4; ++it) {
      const int task = it * 16 + wv;      // 0..63
      const int tl = task >> 1;
      const int hf = task & 1;
      const int ochb = hf * 1024 + l * 16;
      f32x4 v = *(const f32x4*)(smem + tl * 2048 + (ochb ^ ((tl & 7) << 4)));
      *(f32x4*)(out + (size_t)tok_global(blk, th2 * 32 + tl) * 512 + hf * 256 + l * 4) = v;
    }
  }
}

extern "C" void kernel_launch(void* const* d_in, const int* in_sizes, int n_in,
                              void* d_out, int out_size, void* d_ws, size_t ws_size,
                              hipStream_t stream) {
  const float* x  = (const float*)d_in[0];
  const float* wq = (const float*)d_in[1];
  const float* bq = (const float*)d_in[2];
  const float* wp = (const float*)d_in[3];
  const float* bp = (const float*)d_in[4];
  float* out = (float*)d_out;
  u16* wtq = (u16*)d_ws;            // qkv frag-major blob
  u16* wtp = wtq + 512 * 1536;      // proj frag-major blob

  prep_weights<<<2048, 512, 0, stream>>>(wq, wp, wtq, wtp);
  fused_win_attn<<<1024, 1024, 0, stream>>>(x, bq, bp, wtq, wtp, out);
}

// Round 17
// 222.209 us; speedup vs baseline: 3.9841x; 3.9841x over previous
//
#include <hip/hip_runtime.h>

typedef unsigned int u32;
typedef unsigned short u16;
typedef __attribute__((ext_vector_type(4))) float f32x4;
typedef __attribute__((ext_vector_type(8))) short bf16x8;
typedef __attribute__((ext_vector_type(4))) u32 u32x4;

__device__ __forceinline__ u16 f2bf(float f) {
  u32 u = __builtin_bit_cast(u32, f);
  u = u + 0x7FFFu + ((u >> 16) & 1u);
  return (u16)(u >> 16);
}
__device__ __forceinline__ u32 pack2(float a, float b) {
  return (u32)f2bf(a) | ((u32)f2bf(b) << 16);
}
// Pack two C-frags (f32x4 each) into one A/B-frag under the consistent
// k-permutation sigma(8g+p) = 16*(p>>2) + g*4 + (p&3) (+32*kb outside).
// Valid because BOTH operands of the attention-middle MFMAs are packed
// with the same sigma (Q&K for S^T; V&P for O^T).
__device__ __forceinline__ bf16x8 pack8(f32x4 a, f32x4 b) {
  union { u32 w[4]; bf16x8 v; } u;
  u.w[0] = pack2(a[0], a[1]); u.w[1] = pack2(a[2], a[3]);
  u.w[2] = pack2(b[0], b[1]); u.w[3] = pack2(b[2], b[3]);
  return u.v;
}

#define MFMA(a, b, c) __builtin_amdgcn_mfma_f32_16x16x32_bf16((a), (b), (c), 0, 0, 0)

// LDS fragment read: row-major buffer, XOR-swizzled within 128B window.
__device__ __forceinline__ bf16x8 lds_frag(const char* buf, int rowBytes, int row, int kByte) {
  return *(const bf16x8*)(buf + row * rowBytes + (kByte ^ ((row & 7) << 4)));
}

// window/token -> flat token index in [B,32,32,32] (C-contiguous per token)
__device__ __forceinline__ int tok_global(int blk, int t) {
  int b = blk >> 9, r = blk & 511;
  int wd = r >> 6, wh = (r >> 3) & 7, ww = r & 7;
  int d = wd * 4 + (t >> 4);
  int h = wh * 4 + ((t >> 2) & 3);
  int w = ww * 4 + (t & 3);
  return ((b * 32 + d) * 32 + h) * 32 + w;
}

// Weights -> FRAG-MAJOR blob, NATURAL k order within each 32-chunk:
// w[(o_blk*16 + ks)*512 + lane*8 + p] = bf16 of W[ks*32 + g*8 + p][o_blk*16 + lr],
// lane = g*16 + lr. Matches HW A/B-frag mapping (row/col = lane&15,
// k = (lane>>4)*8 + p). Wave frag load = base + lane*8 -> 1KB contiguous.
// This layout was the session's decisive win (R10): it turns each weight
// frag load from a 64-cache-line gather (16B used per 1KB-strided line)
// into a single fully-coalesced 1KB wave access.
__global__ void prep_weights(const float* __restrict__ wq, const float* __restrict__ wp,
                             u16* __restrict__ wtq, u16* __restrict__ wtp) {
  int idx = blockIdx.x * 512 + threadIdx.x;
  if (idx < 512 * 1536) {
    int i = idx / 1536, o = idx % 1536;     // coalesced read of W_qkv[i][o]
    int c = i & 31;                          // k-local, natural order
    int lane = (c >> 3) * 16 + (o & 15);
    wtq[((size_t)(o >> 4) * 16 + (i >> 5)) * 512 + lane * 8 + (c & 7)] = f2bf(wq[idx]);
  } else {
    int j = idx - 512 * 1536;
    int i = j >> 9, o = j & 511;
    int c = i & 31;
    int lane = (c >> 3) * 16 + (o & 15);
    wtp[((size_t)(o >> 4) * 16 + (i >> 5)) * 512 + lane * 8 + (c & 7)] = f2bf(wp[j]);
  }
}

// GEMM pass over 16 K-steps. Weight frags: depth-2 prefetch, 3 static slots
// (48 VGPR), coalesced 1KB/instr. x frags: depth-1 LDS prefetch, 2 slots.
#define GEMM_PASS_AB(WLANE, SMEMBASE)                                         \
  {                                                                           \
    bf16x8 wfs[3][4], bxs[2][4];                                              \
    _Pragma("unroll") for (int i = 0; i < 4; ++i)                             \
        wfs[0][i] = *(const bf16x8*)((WLANE) + (i * 16 + 0) * 512);           \
    _Pragma("unroll") for (int i = 0; i < 4; ++i)                             \
        wfs[1][i] = *(const bf16x8*)((WLANE) + (i * 16 + 1) * 512);           \
    _Pragma("unroll") for (int j = 0; j < 4; ++j)                             \
        bxs[0][j] = lds_frag((SMEMBASE), 1024, j * 16 + lr, g * 16);          \
    _Pragma("unroll") for (int ks = 0; ks < 16; ++ks) {                       \
      if (ks < 15) {                                                          \
        const int kb1 = (ks + 1) * 64 + g * 16;                               \
        _Pragma("unroll") for (int j = 0; j < 4; ++j)                         \
            bxs[(ks + 1) & 1][j] =                                            \
                lds_frag((SMEMBASE), 1024, j * 16 + lr, kb1);                 \
      }                                                                       \
      if (ks < 14) {                                                          \
        _Pragma("unroll") for (int i = 0; i < 4; ++i)                         \
            wfs[(ks + 2) % 3][i] =                                            \
                *(const bf16x8*)((WLANE) + (i * 16 + ks + 2) * 512);          \
      }                                                                       \
      __builtin_amdgcn_s_setprio(1);                                          \
      _Pragma("unroll") for (int i = 0; i < 4; ++i)                           \
        _Pragma("unroll") for (int j = 0; j < 4; ++j)                         \
            acc[i][j] = MFMA(wfs[ks % 3][i], bxs[ks & 1][j], acc[i][j]);      \
      __builtin_amdgcn_s_setprio(0);                                          \
    }                                                                         \
  }
#define GEMM_PASS_BA(WLANE, SMEMBASE)                                         \
  {                                                                           \
    bf16x8 wfs[3][4], bxs[2][4];                                              \
    _Pragma("unroll") for (int i = 0; i < 4; ++i)                             \
        wfs[0][i] = *(const bf16x8*)((WLANE) + (i * 16 + 0) * 512);           \
    _Pragma("unroll") for (int i = 0; i < 4; ++i)                             \
        wfs[1][i] = *(const bf16x8*)((WLANE) + (i * 16 + 1) * 512);           \
    _Pragma("unroll") for (int j = 0; j < 4; ++j)                             \
        bxs[0][j] = lds_frag((SMEMBASE), 1024, j * 16 + lr, g * 16);          \
    _Pragma("unroll") for (int ks = 0; ks < 16; ++ks) {                       \
      if (ks < 15) {                                                          \
        const int kb1 = (ks + 1) * 64 + g * 16;                               \
        _Pragma("unroll") for (int j = 0; j < 4; ++j)                         \
            bxs[(ks + 1) & 1][j] =                                            \
                lds_frag((SMEMBASE), 1024, j * 16 + lr, kb1);                 \
      }                                                                       \
      if (ks < 14) {                                                          \
        _Pragma("unroll") for (int i = 0; i < 4; ++i)                         \
            wfs[(ks + 2) % 3][i] =                                            \
                *(const bf16x8*)((WLANE) + (i * 16 + ks + 2) * 512);          \
      }                                                                       \
      __builtin_amdgcn_s_setprio(1);                                          \
      _Pragma("unroll") for (int i = 0; i < 4; ++i)                           \
        _Pragma("unroll") for (int j = 0; j < 4; ++j)                         \
            acc[i][j] = MFMA(bxs[ks & 1][i], wfs[ks % 3][j], acc[i][j]);      \
      __builtin_amdgcn_s_setprio(0);                                          \
    }                                                                         \
  }

__global__ __launch_bounds__(512, 2) void fused_win_attn(
    const float* __restrict__ x, const float* __restrict__ bq, const float* __restrict__ bp,
    const u16* __restrict__ wtq, const u16* __restrict__ wtp, float* __restrict__ out) {
  // LDS: x [64 tok][512 ch] bf16 swizzled; -> O (same layout) after V pass;
  // -> Y staging [32 tok][512 ch] f32 (two halves) in the epilogue.
  __shared__ char smem[65536];
  const int tid = threadIdx.x;
  const int wv = tid >> 6;   // wave id == head id
  const int l  = tid & 63;
  const int lr = l & 15;
  const int g  = l >> 4;
  const int blk = blockIdx.x;

  // ---- stage x -> LDS bf16 (once; 1 barrier) ----
  {
    const int st = tid >> 3, seg = tid & 7;       // token row, 64-ch segment
    const float* xs = x + (size_t)tok_global(blk, st) * 512 + seg * 64;
    char* dst = smem + st * 1024;
    const int swz = (st & 7) << 4;
    float4 f[16];
#pragma unroll
    for (int i = 0; i < 16; ++i) f[i] = ((const float4*)xs)[i];
#pragma unroll
    for (int i = 0; i < 8; ++i) {
      const int ic = (i + seg) & 7;   // rotate across bank quads per phase
      u32x4 w = {pack2(f[2 * ic].x, f[2 * ic].y),         pack2(f[2 * ic].z, f[2 * ic].w),
                 pack2(f[2 * ic + 1].x, f[2 * ic + 1].y), pack2(f[2 * ic + 1].z, f[2 * ic + 1].w)};
      *(u32x4*)(dst + ((seg * 128 + ic * 16) ^ swz)) = w;
    }
  }
  __syncthreads();

  // per-lane weight base pointers into the frag-major blobs
  const u16* wqL = wtq + ((size_t)wv * 4 * 16) * 512 + l * 8;
  const u16* wkL = wqL + (size_t)512 * 512;    // +32 o_blks (och +512)
  const u16* wvL = wqL + (size_t)1024 * 512;   // +64 o_blks (och +1024)
  const u16* wpL = wtp + ((size_t)wv * 4 * 16) * 512 + l * 8;

  bf16x8 qp[4][2], ka[4][2], pb[4][2], va[4][2];
  f32x4 acc[4][4];

  // ======== Q pass: Q [d=64][t=64] (M=och, N=t, K=ch 512) ========
#pragma unroll
  for (int i = 0; i < 4; ++i)
#pragma unroll
    for (int j = 0; j < 4; ++j) acc[i][j] = (f32x4)0.f;
  GEMM_PASS_AB(wqL, smem);
#pragma unroll
  for (int i = 0; i < 4; ++i) {
    const int och = wv * 64 + i * 16 + g * 4;
    f32x4 qb = {bq[och], bq[och + 1], bq[och + 2], bq[och + 3]};
#pragma unroll
    for (int j = 0; j < 4; ++j) acc[i][j] += qb;
  }
#pragma unroll
  for (int j = 0; j < 4; ++j)
#pragma unroll
    for (int kb = 0; kb < 2; ++kb)
      qp[j][kb] = pack8(acc[2 * kb][j], acc[2 * kb + 1][j]);   // B-frag: col t, k=d

  // ======== K pass ========
#pragma unroll
  for (int i = 0; i < 4; ++i)
#pragma unroll
    for (int j = 0; j < 4; ++j) acc[i][j] = (f32x4)0.f;
  GEMM_PASS_AB(wkL, smem);
#pragma unroll
  for (int i = 0; i < 4; ++i) {
    const int och = 512 + wv * 64 + i * 16 + g * 4;
    f32x4 kb = {bq[och], bq[och + 1], bq[och + 2], bq[och + 3]};
#pragma unroll
    for (int j = 0; j < 4; ++j) acc[i][j] += kb;
  }
#pragma unroll
  for (int m = 0; m < 4; ++m)
#pragma unroll
    for (int kb = 0; kb < 2; ++kb)
      ka[m][kb] = pack8(acc[2 * kb][m], acc[2 * kb + 1][m]);   // A-frag: row s, k=d

  // ======== S^T = K-rows x Q (M=s, N=t, K=d=64): pure register MFMA ========
  {
    f32x4 sacc[4][4];
#pragma unroll
    for (int m = 0; m < 4; ++m)
#pragma unroll
      for (int j = 0; j < 4; ++j) {
        f32x4 a = (f32x4)0.f;
        a = MFMA(ka[m][0], qp[j][0], a);
        sacc[m][j] = MFMA(ka[m][1], qp[j][1], a);
      }
    // scale + clip + softmax over s (16 local + xor16 + xor32)
#pragma unroll
    for (int m = 0; m < 4; ++m)
#pragma unroll
      for (int j = 0; j < 4; ++j)
#pragma unroll
        for (int r = 0; r < 4; ++r) {
          float v = sacc[m][j][r] * 0.125f;
          sacc[m][j][r] = fminf(fmaxf(v, -10000.f), 10000.f);
        }
    float mx[4], sm[4];
#pragma unroll
    for (int j = 0; j < 4; ++j) {
      float a0 = fmaxf(fmaxf(sacc[0][j][0], sacc[0][j][1]), fmaxf(sacc[0][j][2], sacc[0][j][3]));
      float a1 = fmaxf(fmaxf(sacc[1][j][0], sacc[1][j][1]), fmaxf(sacc[1][j][2], sacc[1][j][3]));
      float a2 = fmaxf(fmaxf(sacc[2][j][0], sacc[2][j][1]), fmaxf(sacc[2][j][2], sacc[2][j][3]));
      float a3 = fmaxf(fmaxf(sacc[3][j][0], sacc[3][j][1]), fmaxf(sacc[3][j][2], sacc[3][j][3]));
      mx[j] = fmaxf(fmaxf(a0, a1), fmaxf(a2, a3));
    }
#pragma unroll
    for (int j = 0; j < 4; ++j) mx[j] = fmaxf(mx[j], __shfl_xor(mx[j], 16));
#pragma unroll
    for (int j = 0; j < 4; ++j) mx[j] = fmaxf(mx[j], __shfl_xor(mx[j], 32));
#pragma unroll
    for (int j = 0; j < 4; ++j) {
      float s0 = 0.f;
#pragma unroll
      for (int m = 0; m < 4; ++m)
#pragma unroll
        for (int r = 0; r < 4; ++r) {
          float p = __expf(sacc[m][j][r] - mx[j]);
          sacc[m][j][r] = p;
          s0 += p;
        }
      sm[j] = s0;
    }
#pragma unroll
    for (int j = 0; j < 4; ++j) sm[j] += __shfl_xor(sm[j], 16);
#pragma unroll
    for (int j = 0; j < 4; ++j) sm[j] += __shfl_xor(sm[j], 32);
#pragma unroll
    for (int j = 0; j < 4; ++j) {
      float inv = 1.f / sm[j];
#pragma unroll
      for (int kb = 0; kb < 2; ++kb)
        pb[j][kb] = pack8(sacc[2 * kb][j] * inv, sacc[2 * kb + 1][j] * inv);  // B-frag
    }
  }

  // ======== V pass: V [s=64][d=64] (M=t(=s), N=d, K=ch 512) ========
#pragma unroll
  for (int i = 0; i < 4; ++i)
#pragma unroll
    for (int j = 0; j < 4; ++j) acc[i][j] = (f32x4)0.f;
  GEMM_PASS_BA(wvL, smem);
#pragma unroll
  for (int ni = 0; ni < 4; ++ni) {
    float bv = bq[1024 + wv * 64 + ni * 16 + lr];
#pragma unroll
    for (int ti = 0; ti < 4; ++ti) acc[ti][ni] += (f32x4)bv;
#pragma unroll
    for (int kb = 0; kb < 2; ++kb)
      va[ni][kb] = pack8(acc[2 * kb][ni], acc[2 * kb + 1][ni]);  // A-frag: row d, k=s
  }

  // ---- all x reads done; switch LDS to O [t][512] bf16 ----
  __syncthreads();

  // ======== O^T = V^T x P^T (M=d, N=t, K=s=64) + write O to LDS ========
#pragma unroll
  for (int ni = 0; ni < 4; ++ni)
#pragma unroll
    for (int j = 0; j < 4; ++j) {
      f32x4 a = (f32x4)0.f;
      a = MFMA(va[ni][0], pb[j][0], a);
      a = MFMA(va[ni][1], pb[j][1], a);
      int t = j * 16 + lr;
      int cb = (wv * 64 + ni * 16 + g * 4) * 2;
      int swz = (t & 7) << 4;
      *(u32*)(smem + t * 1024 + (cb ^ swz))       = pack2(a[0], a[1]);
      *(u32*)(smem + t * 1024 + ((cb + 4) ^ swz)) = pack2(a[2], a[3]);
    }
  __syncthreads();

  // ======== Y = O @ Wproj (M=och, N=t, K=ch 512) ========
#pragma unroll
  for (int i = 0; i < 4; ++i)
#pragma unroll
    for (int j = 0; j < 4; ++j) acc[i][j] = (f32x4)0.f;
  GEMM_PASS_AB(wpL, smem);
  // +bias into acc
#pragma unroll
  for (int mi = 0; mi < 4; ++mi) {
    const int och = wv * 64 + mi * 16 + g * 4;
    f32x4 bb = {bp[och], bp[och + 1], bp[och + 2], bp[och + 3]};
#pragma unroll
    for (int tj = 0; tj < 4; ++tj) acc[mi][tj] += bb;
  }

  // ======== Epilogue: stage Y via LDS, fully coalesced f32 stores ========
  // Two halves of 32 tokens; LDS as [32 tok][512 och] f32 (64KB), XOR-swizzled.
#pragma unroll
  for (int th = 0; th < 2; ++th) {
    __syncthreads();   // th=0: all waves done reading O; th=1: done reading half 0
#pragma unroll
    for (int mi = 0; mi < 4; ++mi)
#pragma unroll
      for (int jj = 0; jj < 2; ++jj) {
        const int tj = th * 2 + jj;
        const int tl = (tj * 16 + lr) & 31;                 // token within half
        const int ochb = (wv * 64 + mi * 16 + g * 4) * 4;   // byte offset of och
        *(f32x4*)(smem + tl * 2048 + (ochb ^ ((tl & 7) << 4))) = acc[mi][tj];
      }
    __syncthreads();
    // store: each wave-iteration writes 1KB contiguous (half a token's channels)
#pragma unroll
    for (int it = 0; it < 8; ++it) {
      const int task = it * 8 + wv;       // 0..63
      const int tl = task >> 1;           // 0..31
      const int hf = task & 1;            // which 1KB half of the 2KB token row
      const int ochb = hf * 1024 + l * 16;
      f32x4 v = *(const f32x4*)(smem + tl * 2048 + (ochb ^ ((tl & 7) << 4)));
      *(f32x4*)(out + (size_t)tok_global(blk, th * 32 + tl) * 512 + hf * 256 + l * 4) = v;
    }
  }
}

extern "C" void kernel_launch(void* const* d_in, const int* in_sizes, int n_in,
                              void* d_out, int out_size, void* d_ws, size_t ws_size,
                              hipStream_t stream) {
  const float* x  = (const float*)d_in[0];
  const float* wq = (const float*)d_in[1];
  const float* bq = (const float*)d_in[2];
  const float* wp = (const float*)d_in[3];
  const float* bp = (const float*)d_in[4];
  float* out = (float*)d_out;
  u16* wtq = (u16*)d_ws;            // qkv frag-major blob: 96 o_blks x 16 ks x 512
  u16* wtp = wtq + 512 * 1536;      // proj frag-major blob: 32 o_blks x 16 ks x 512

  prep_weights<<<2048, 512, 0, stream>>>(wq, wp, wtq, wtp);
  fused_win_attn<<<1024, 512, 0, stream>>>(x, bq, bp, wtq, wtp, out);
}